// Round 1
// baseline (935.843 us; speedup 1.0000x reference)
//
#include <hip/hip_runtime.h>

// GIN_MLP: 2x GIN conv (N=100000, E=1.6M, H=128) + per-batch context MLP (B=4096).
// Strategy: device-built dst-CSR (no float atomics) -> fused aggregate+GEMM per
// 64-node tile -> small per-batch-element MLP. All f32 (no f32 MFMA on CDNA4;
// 2e-2 absmax budget makes bf16 risky).

#define CONV_NPB 64

__global__ void prep_transpose(const float* __restrict__ W1, const float* __restrict__ W2,
                               const float* __restrict__ Wc1, const float* __restrict__ Wc2,
                               float* __restrict__ Wt1, float* __restrict__ Wt2,
                               float* __restrict__ Wc1t, float* __restrict__ Wc2t) {
  int i = blockIdx.x * blockDim.x + threadIdx.x;
  if (i < 16384) {
    int f = i >> 7, k = i & 127;
    Wt1[k * 128 + f] = W1[i];
  } else if (i < 32768) {
    int j = i - 16384; int f = j >> 7, k = j & 127;
    Wt2[k * 128 + f] = W2[j];
  } else if (i < 81920) {
    int j = i - 32768; int f = j / 384, k = j % 384;
    Wc1t[k * 128 + f] = Wc1[j];
  } else if (i < 90112) {
    int j = i - 81920; int f = j >> 7, k = j & 127;
    Wc2t[k * 64 + f] = Wc2[j];
  }
}

__global__ void hist_kernel(const int* __restrict__ dst, int* __restrict__ cnt, int E) {
  int e = blockIdx.x * blockDim.x + threadIdx.x;
  if (e < E) atomicAdd(&cnt[dst[e]], 1);
}

// per-2048-chunk exclusive scan; bsum[b] = chunk total
__global__ void scan1_kernel(const int* __restrict__ cnt, int* __restrict__ rowptr,
                             int* __restrict__ bsum, int n) {
  __shared__ int smem[256];
  const int t = threadIdx.x;
  const int base = blockIdx.x * 2048 + t * 8;
  int v[8];
  int s = 0;
#pragma unroll
  for (int j = 0; j < 8; ++j) {
    int idx = base + j;
    v[j] = (idx < n) ? cnt[idx] : 0;
    s += v[j];
  }
  smem[t] = s;
  __syncthreads();
  for (int off = 1; off < 256; off <<= 1) {
    int add = (t >= off) ? smem[t - off] : 0;
    __syncthreads();
    smem[t] += add;
    __syncthreads();
  }
  int run = smem[t] - s;  // exclusive prefix of this thread within block
  if (t == 255) bsum[blockIdx.x] = smem[255];
#pragma unroll
  for (int j = 0; j < 8; ++j) {
    int idx = base + j;
    if (idx < n) rowptr[idx] = run;
    run += v[j];
  }
}

__global__ void scan2_kernel(int* __restrict__ bsum, int nb) {
  if (threadIdx.x == 0 && blockIdx.x == 0) {
    int run = 0;
    for (int i = 0; i < nb; ++i) { int v = bsum[i]; bsum[i] = run; run += v; }
  }
}

__global__ void scan3_kernel(int* __restrict__ rowptr, const int* __restrict__ bsum,
                             int n, int E) {
  int i = blockIdx.x * blockDim.x + threadIdx.x;
  if (i < n) rowptr[i] += bsum[i >> 11];
  if (i == 0) rowptr[n] = E;
}

__global__ void scatter_kernel(const int* __restrict__ src, const int* __restrict__ dst,
                               const float* __restrict__ w, const int* __restrict__ rowptr,
                               int* __restrict__ cursor, int* __restrict__ esrc,
                               float* __restrict__ ew, int E) {
  int e = blockIdx.x * blockDim.x + threadIdx.x;
  if (e < E) {
    int d = dst[e];
    int pos = rowptr[d] + atomicAdd(&cursor[d], 1);
    esrc[pos] = src[e];
    ew[pos] = w[e];
  }
}

// Fused: stage 1 aggregates 64 node rows ((1+eps)x + agg/deg) into LDS,
// stage 2 does the 64x128 @ 128x128 f32 GEMM with register tiling 8x4.
__launch_bounds__(256, 4)
__global__ void conv_kernel(const float* __restrict__ xin, float* __restrict__ xout,
                            const int* __restrict__ rowptr, const int* __restrict__ esrc,
                            const float* __restrict__ ew, const float* __restrict__ Wt,
                            const float* __restrict__ bias, const float* __restrict__ eps,
                            int epsidx, int dorelu, int zerorow0, int n) {
  __shared__ float xm[CONV_NPB * 128];
  const int t = threadIdx.x;
  const int nb = blockIdx.x * CONV_NPB;
  const float epsv = 1.0f + eps[epsidx];

  // ---- stage 1: gather/aggregate ----
  {
    const int f = t & 127;
    const int half = t >> 7;  // 0 or 1
    for (int r = half * 32; r < half * 32 + 32; ++r) {
      const int node = nb + r;
      float val = 0.0f;
      if (node < n) {
        const int e0 = rowptr[node];
        const int e1 = rowptr[node + 1];
        float acc = 0.0f;
        int j = e0;
        for (; j + 4 <= e1; j += 4) {
          const int s0 = esrc[j + 0], s1 = esrc[j + 1], s2 = esrc[j + 2], s3 = esrc[j + 3];
          const float w0 = ew[j + 0], w1 = ew[j + 1], w2 = ew[j + 2], w3 = ew[j + 3];
          const float a0 = xin[(size_t)s0 * 128 + f];
          const float a1 = xin[(size_t)s1 * 128 + f];
          const float a2 = xin[(size_t)s2 * 128 + f];
          const float a3 = xin[(size_t)s3 * 128 + f];
          acc += w0 * a0 + w1 * a1 + w2 * a2 + w3 * a3;
        }
        for (; j < e1; ++j) acc += ew[j] * xin[(size_t)esrc[j] * 128 + f];
        const int d = e1 - e0;
        const float deg = (float)(d > 1 ? d : 1);
        val = epsv * xin[(size_t)node * 128 + f] + acc / deg;
      }
      xm[r * 128 + f] = val;
    }
  }
  __syncthreads();

  // ---- stage 2: GEMM, thread tile = 8 rows x 4 features ----
  {
    const int fg = t & 31;
    const int rg = t >> 5;
    const int f0 = fg * 4;
    const int r0 = rg * 8;
    float4 acc[8];
#pragma unroll
    for (int r = 0; r < 8; ++r) acc[r] = make_float4(0.f, 0.f, 0.f, 0.f);
    for (int k = 0; k < 128; k += 4) {
      const float4 w0 = *(const float4*)&Wt[(k + 0) * 128 + f0];
      const float4 w1 = *(const float4*)&Wt[(k + 1) * 128 + f0];
      const float4 w2 = *(const float4*)&Wt[(k + 2) * 128 + f0];
      const float4 w3 = *(const float4*)&Wt[(k + 3) * 128 + f0];
#pragma unroll
      for (int r = 0; r < 8; ++r) {
        const float4 xv = *(const float4*)&xm[(r0 + r) * 128 + k];
        acc[r].x += xv.x * w0.x + xv.y * w1.x + xv.z * w2.x + xv.w * w3.x;
        acc[r].y += xv.x * w0.y + xv.y * w1.y + xv.z * w2.y + xv.w * w3.y;
        acc[r].z += xv.x * w0.z + xv.y * w1.z + xv.z * w2.z + xv.w * w3.z;
        acc[r].w += xv.x * w0.w + xv.y * w1.w + xv.z * w2.w + xv.w * w3.w;
      }
    }
    const float4 bv = *(const float4*)&bias[f0];
#pragma unroll
    for (int r = 0; r < 8; ++r) {
      const int node = nb + r0 + r;
      if (node < n) {
        float4 v;
        v.x = acc[r].x + bv.x;
        v.y = acc[r].y + bv.y;
        v.z = acc[r].z + bv.z;
        v.w = acc[r].w + bv.w;
        if (dorelu) {
          v.x = fmaxf(v.x, 0.f); v.y = fmaxf(v.y, 0.f);
          v.z = fmaxf(v.z, 0.f); v.w = fmaxf(v.w, 0.f);
        }
        if (zerorow0 && node == 0) { v.x = 0.f; v.y = 0.f; v.z = 0.f; v.w = 0.f; }
        *(float4*)&xout[(size_t)node * 128 + f0] = v;
      }
    }
  }
}

// One block (128 thr) per batch element: gather ing1/ing2/ctx into LDS, MLP 384->128->64->1.
__launch_bounds__(128, 4)
__global__ void final_kernel(const float* __restrict__ x2, const int* __restrict__ indices,
                             const float* __restrict__ Wc1t, const float* __restrict__ bc1,
                             const float* __restrict__ Wc2t, const float* __restrict__ bc2,
                             const float* __restrict__ Wc3, const float* __restrict__ bc3,
                             float* __restrict__ out) {
  __shared__ float ysm[384];
  __shared__ float h1s[128];
  const int b = blockIdx.x;
  const int t = threadIdx.x;
  const int* ind = indices + (size_t)b * 23;

  {
    const int i0 = ind[0];
    const int i1 = ind[1];
    ysm[t] = x2[(size_t)i0 * 128 + t];          // x2 row 0 is zeroed -> matches x.at[0].set(0)
    ysm[128 + t] = x2[(size_t)i1 * 128 + t];
    float cs = 0.f;
    int cc = 0;
#pragma unroll
    for (int j = 0; j < 20; ++j) {
      const int cj = ind[3 + j];
      cc += (cj > 0) ? 1 : 0;
      cs += x2[(size_t)cj * 128 + t];
    }
    ysm[256 + t] = cs / (float)(cc > 0 ? cc : 1);
  }
  __syncthreads();

  {
    float acc = bc1[t];
    for (int k = 0; k < 384; k += 4) {
      const float4 yv = *(const float4*)&ysm[k];
      acc += yv.x * Wc1t[(k + 0) * 128 + t];
      acc += yv.y * Wc1t[(k + 1) * 128 + t];
      acc += yv.z * Wc1t[(k + 2) * 128 + t];
      acc += yv.w * Wc1t[(k + 3) * 128 + t];
    }
    h1s[t] = fmaxf(acc, 0.f);
  }
  __syncthreads();

  if (t < 64) {
    float acc = bc2[t];
    for (int k = 0; k < 128; k += 4) {
      const float4 hv = *(const float4*)&h1s[k];
      acc += hv.x * Wc2t[(k + 0) * 64 + t];
      acc += hv.y * Wc2t[(k + 1) * 64 + t];
      acc += hv.z * Wc2t[(k + 2) * 64 + t];
      acc += hv.w * Wc2t[(k + 3) * 64 + t];
    }
    float v = fmaxf(acc, 0.f) * Wc3[t];
#pragma unroll
    for (int o = 32; o > 0; o >>= 1) v += __shfl_down(v, o);
    if (t == 0) out[b] = v + bc3[0];
  }
}

extern "C" void kernel_launch(void* const* d_in, const int* in_sizes, int n_in,
                              void* d_out, int out_size, void* d_ws, size_t ws_size,
                              hipStream_t stream) {
  const int* indices = (const int*)d_in[0];
  const int* src = (const int*)d_in[1];
  const int* dst = (const int*)d_in[2];
  const float* w = (const float*)d_in[3];
  const float* ndata = (const float*)d_in[4];
  const float* W1 = (const float*)d_in[5];
  const float* b1 = (const float*)d_in[6];
  const float* W2 = (const float*)d_in[7];
  const float* b2 = (const float*)d_in[8];
  const float* eps = (const float*)d_in[9];
  const float* Wc1 = (const float*)d_in[10];
  const float* bc1 = (const float*)d_in[11];
  const float* Wc2 = (const float*)d_in[12];
  const float* bc2 = (const float*)d_in[13];
  const float* Wc3 = (const float*)d_in[14];
  const float* bc3 = (const float*)d_in[15];
  float* out = (float*)d_out;

  const int E = in_sizes[1];
  const int N = in_sizes[4] / 128;
  const int B = in_sizes[0] / 23;

  char* ws = (char*)d_ws;
  size_t off = 0;
  auto alloc = [&](size_t bytes) -> char* {
    char* p = ws + off;
    off = (off + bytes + 255) & ~(size_t)255;
    return p;
  };
  int* cnt = (int*)alloc((size_t)N * 4);
  int* rowptr = (int*)alloc((size_t)(N + 1) * 4);
  int* cursor = (int*)alloc((size_t)N * 4);
  int* bsum = (int*)alloc(256 * 4);
  int* esrc = (int*)alloc((size_t)E * 4);
  float* ewv = (float*)alloc((size_t)E * 4);
  float* x1 = (float*)alloc((size_t)N * 128 * 4);
  float* x2 = (float*)alloc((size_t)N * 128 * 4);
  float* Wt1 = (float*)alloc(16384 * 4);
  float* Wt2 = (float*)alloc(16384 * 4);
  float* Wc1t = (float*)alloc(49152 * 4);
  float* Wc2t = (float*)alloc(8192 * 4);

  hipMemsetAsync(cnt, 0, (size_t)N * 4, stream);
  hipMemsetAsync(cursor, 0, (size_t)N * 4, stream);

  prep_transpose<<<(90112 + 255) / 256, 256, 0, stream>>>(W1, W2, Wc1, Wc2, Wt1, Wt2, Wc1t, Wc2t);
  hist_kernel<<<(E + 255) / 256, 256, 0, stream>>>(dst, cnt, E);
  const int nchunk = (N + 2047) / 2048;
  scan1_kernel<<<nchunk, 256, 0, stream>>>(cnt, rowptr, bsum, N);
  scan2_kernel<<<1, 64, 0, stream>>>(bsum, nchunk);
  scan3_kernel<<<(N + 255) / 256, 256, 0, stream>>>(rowptr, bsum, N, E);
  scatter_kernel<<<(E + 255) / 256, 256, 0, stream>>>(src, dst, w, rowptr, cursor, esrc, ewv, E);

  const int nconv = (N + CONV_NPB - 1) / CONV_NPB;
  conv_kernel<<<nconv, 256, 0, stream>>>(ndata, x1, rowptr, esrc, ewv, Wt1, b1, eps, 0, 1, 0, N);
  conv_kernel<<<nconv, 256, 0, stream>>>(x1, x2, rowptr, esrc, ewv, Wt2, b2, eps, 1, 0, 1, N);

  final_kernel<<<B, 128, 0, stream>>>(x2, indices, Wc1t, bc1, Wc2t, bc2, Wc3, bc3, out);
}

// Round 2
// 682.564 us; speedup vs baseline: 1.3711x; 1.3711x over previous
//
#include <hip/hip_runtime.h>

// GIN_MLP: 2x GIN conv (N=100000, E=1.6M, H=128) + per-batch context MLP (B=4096).
// Strategy: device-built dst-CSR (no float atomics) -> fused aggregate+GEMM per
// 64-node tile -> small per-batch-element MLP. All f32 (no f32 MFMA on CDNA4;
// 2e-2 absmax budget makes bf16 risky).
// R2: float4 gather (16B/lane), packed (src,w) int2 edge stream, occupancy 5 blk/CU.

#define CONV_NPB 64

__global__ void prep_transpose(const float* __restrict__ W1, const float* __restrict__ W2,
                               const float* __restrict__ Wc1, const float* __restrict__ Wc2,
                               float* __restrict__ Wt1, float* __restrict__ Wt2,
                               float* __restrict__ Wc1t, float* __restrict__ Wc2t) {
  int i = blockIdx.x * blockDim.x + threadIdx.x;
  if (i < 16384) {
    int f = i >> 7, k = i & 127;
    Wt1[k * 128 + f] = W1[i];
  } else if (i < 32768) {
    int j = i - 16384; int f = j >> 7, k = j & 127;
    Wt2[k * 128 + f] = W2[j];
  } else if (i < 81920) {
    int j = i - 32768; int f = j / 384, k = j % 384;
    Wc1t[k * 128 + f] = Wc1[j];
  } else if (i < 90112) {
    int j = i - 81920; int f = j >> 7, k = j & 127;
    Wc2t[k * 64 + f] = Wc2[j];
  }
}

__global__ void hist_kernel(const int* __restrict__ dst, int* __restrict__ cnt, int E) {
  int e = blockIdx.x * blockDim.x + threadIdx.x;
  if (e < E) atomicAdd(&cnt[dst[e]], 1);
}

// per-2048-chunk exclusive scan; bsum[b] = chunk total
__global__ void scan1_kernel(const int* __restrict__ cnt, int* __restrict__ rowptr,
                             int* __restrict__ bsum, int n) {
  __shared__ int smem[256];
  const int t = threadIdx.x;
  const int base = blockIdx.x * 2048 + t * 8;
  int v[8];
  int s = 0;
#pragma unroll
  for (int j = 0; j < 8; ++j) {
    int idx = base + j;
    v[j] = (idx < n) ? cnt[idx] : 0;
    s += v[j];
  }
  smem[t] = s;
  __syncthreads();
  for (int off = 1; off < 256; off <<= 1) {
    int add = (t >= off) ? smem[t - off] : 0;
    __syncthreads();
    smem[t] += add;
    __syncthreads();
  }
  int run = smem[t] - s;  // exclusive prefix of this thread within block
  if (t == 255) bsum[blockIdx.x] = smem[255];
#pragma unroll
  for (int j = 0; j < 8; ++j) {
    int idx = base + j;
    if (idx < n) rowptr[idx] = run;
    run += v[j];
  }
}

__global__ void scan2_kernel(int* __restrict__ bsum, int nb) {
  if (threadIdx.x == 0 && blockIdx.x == 0) {
    int run = 0;
    for (int i = 0; i < nb; ++i) { int v = bsum[i]; bsum[i] = run; run += v; }
  }
}

__global__ void scan3_kernel(int* __restrict__ rowptr, const int* __restrict__ bsum,
                             int n, int E) {
  int i = blockIdx.x * blockDim.x + threadIdx.x;
  if (i < n) rowptr[i] += bsum[i >> 11];
  if (i == 0) rowptr[n] = E;
}

// packs (src, bitcast(w)) so the conv edge stream is one 8B load per edge
__global__ void scatter_kernel(const int* __restrict__ src, const int* __restrict__ dst,
                               const float* __restrict__ w, const int* __restrict__ rowptr,
                               int* __restrict__ cursor, int2* __restrict__ epack, int E) {
  int e = blockIdx.x * blockDim.x + threadIdx.x;
  if (e < E) {
    int d = dst[e];
    int pos = rowptr[d] + atomicAdd(&cursor[d], 1);
    epack[pos] = make_int2(src[e], __float_as_int(w[e]));
  }
}

// Fused: stage 1 aggregates 64 node rows ((1+eps)x + agg/deg) into LDS with
// float4 gathers (thread = 4 features x 8 rows), stage 2 does the
// 64x128 @ 128x128 f32 GEMM with register tiling 8x4.
__launch_bounds__(256, 5)
__global__ void conv_kernel(const float* __restrict__ xin, float* __restrict__ xout,
                            const int* __restrict__ rowptr, const int2* __restrict__ epack,
                            const float* __restrict__ Wt,
                            const float* __restrict__ bias, const float* __restrict__ eps,
                            int epsidx, int dorelu, int zerorow0, int n) {
  __shared__ float xm[CONV_NPB * 128];
  const int t = threadIdx.x;
  const int nb = blockIdx.x * CONV_NPB;
  const float epsv = 1.0f + eps[epsidx];

  // ---- stage 1: gather/aggregate, float4 per lane ----
  {
    const int fg = t & 31;   // feature group: 4 consecutive floats
    const int rg = t >> 5;   // row group: 8 rows
    const int f0 = fg * 4;
#pragma unroll 1
    for (int rr = 0; rr < 8; ++rr) {
      const int r = rg * 8 + rr;
      const int node = nb + r;
      float4 val = make_float4(0.f, 0.f, 0.f, 0.f);
      if (node < n) {
        const int e0 = rowptr[node];
        const int e1 = rowptr[node + 1];
        float ax = 0.f, ay = 0.f, az = 0.f, aw = 0.f;
        int j = e0;
        for (; j + 4 <= e1; j += 4) {
          const int2 p0 = epack[j + 0];
          const int2 p1 = epack[j + 1];
          const int2 p2 = epack[j + 2];
          const int2 p3 = epack[j + 3];
          const float4 a0 = *(const float4*)&xin[(size_t)p0.x * 128 + f0];
          const float4 a1 = *(const float4*)&xin[(size_t)p1.x * 128 + f0];
          const float4 a2 = *(const float4*)&xin[(size_t)p2.x * 128 + f0];
          const float4 a3 = *(const float4*)&xin[(size_t)p3.x * 128 + f0];
          const float w0 = __int_as_float(p0.y), w1 = __int_as_float(p1.y);
          const float w2 = __int_as_float(p2.y), w3 = __int_as_float(p3.y);
          ax += w0 * a0.x + w1 * a1.x + w2 * a2.x + w3 * a3.x;
          ay += w0 * a0.y + w1 * a1.y + w2 * a2.y + w3 * a3.y;
          az += w0 * a0.z + w1 * a1.z + w2 * a2.z + w3 * a3.z;
          aw += w0 * a0.w + w1 * a1.w + w2 * a2.w + w3 * a3.w;
        }
        for (; j < e1; ++j) {
          const int2 p = epack[j];
          const float4 a = *(const float4*)&xin[(size_t)p.x * 128 + f0];
          const float wv = __int_as_float(p.y);
          ax += wv * a.x; ay += wv * a.y; az += wv * a.z; aw += wv * a.w;
        }
        const int d = e1 - e0;
        const float rdeg = 1.0f / (float)(d > 1 ? d : 1);
        const float4 xv = *(const float4*)&xin[(size_t)node * 128 + f0];
        val.x = epsv * xv.x + ax * rdeg;
        val.y = epsv * xv.y + ay * rdeg;
        val.z = epsv * xv.z + az * rdeg;
        val.w = epsv * xv.w + aw * rdeg;
      }
      *(float4*)&xm[r * 128 + f0] = val;
    }
  }
  __syncthreads();

  // ---- stage 2: GEMM, thread tile = 8 rows x 4 features ----
  {
    const int fg = t & 31;
    const int rg = t >> 5;
    const int f0 = fg * 4;
    const int r0 = rg * 8;
    float4 acc[8];
#pragma unroll
    for (int r = 0; r < 8; ++r) acc[r] = make_float4(0.f, 0.f, 0.f, 0.f);
    for (int k = 0; k < 128; k += 4) {
      const float4 w0 = *(const float4*)&Wt[(k + 0) * 128 + f0];
      const float4 w1 = *(const float4*)&Wt[(k + 1) * 128 + f0];
      const float4 w2 = *(const float4*)&Wt[(k + 2) * 128 + f0];
      const float4 w3 = *(const float4*)&Wt[(k + 3) * 128 + f0];
#pragma unroll
      for (int r = 0; r < 8; ++r) {
        const float4 xv = *(const float4*)&xm[(r0 + r) * 128 + k];
        acc[r].x += xv.x * w0.x + xv.y * w1.x + xv.z * w2.x + xv.w * w3.x;
        acc[r].y += xv.x * w0.y + xv.y * w1.y + xv.z * w2.y + xv.w * w3.y;
        acc[r].z += xv.x * w0.z + xv.y * w1.z + xv.z * w2.z + xv.w * w3.z;
        acc[r].w += xv.x * w0.w + xv.y * w1.w + xv.z * w2.w + xv.w * w3.w;
      }
    }
    const float4 bv = *(const float4*)&bias[f0];
#pragma unroll
    for (int r = 0; r < 8; ++r) {
      const int node = nb + r0 + r;
      if (node < n) {
        float4 v;
        v.x = acc[r].x + bv.x;
        v.y = acc[r].y + bv.y;
        v.z = acc[r].z + bv.z;
        v.w = acc[r].w + bv.w;
        if (dorelu) {
          v.x = fmaxf(v.x, 0.f); v.y = fmaxf(v.y, 0.f);
          v.z = fmaxf(v.z, 0.f); v.w = fmaxf(v.w, 0.f);
        }
        if (zerorow0 && node == 0) { v.x = 0.f; v.y = 0.f; v.z = 0.f; v.w = 0.f; }
        *(float4*)&xout[(size_t)node * 128 + f0] = v;
      }
    }
  }
}

// One block (128 thr) per batch element: gather ing1/ing2/ctx into LDS, MLP 384->128->64->1.
__launch_bounds__(128, 4)
__global__ void final_kernel(const float* __restrict__ x2, const int* __restrict__ indices,
                             const float* __restrict__ Wc1t, const float* __restrict__ bc1,
                             const float* __restrict__ Wc2t, const float* __restrict__ bc2,
                             const float* __restrict__ Wc3, const float* __restrict__ bc3,
                             float* __restrict__ out) {
  __shared__ float ysm[384];
  __shared__ float h1s[128];
  const int b = blockIdx.x;
  const int t = threadIdx.x;
  const int* ind = indices + (size_t)b * 23;

  {
    const int i0 = ind[0];
    const int i1 = ind[1];
    ysm[t] = x2[(size_t)i0 * 128 + t];          // x2 row 0 is zeroed -> matches x.at[0].set(0)
    ysm[128 + t] = x2[(size_t)i1 * 128 + t];
    float cs = 0.f;
    int cc = 0;
#pragma unroll
    for (int j = 0; j < 20; ++j) {
      const int cj = ind[3 + j];
      cc += (cj > 0) ? 1 : 0;
      cs += x2[(size_t)cj * 128 + t];
    }
    ysm[256 + t] = cs / (float)(cc > 0 ? cc : 1);
  }
  __syncthreads();

  {
    float acc = bc1[t];
    for (int k = 0; k < 384; k += 4) {
      const float4 yv = *(const float4*)&ysm[k];
      acc += yv.x * Wc1t[(k + 0) * 128 + t];
      acc += yv.y * Wc1t[(k + 1) * 128 + t];
      acc += yv.z * Wc1t[(k + 2) * 128 + t];
      acc += yv.w * Wc1t[(k + 3) * 128 + t];
    }
    h1s[t] = fmaxf(acc, 0.f);
  }
  __syncthreads();

  if (t < 64) {
    float acc = bc2[t];
    for (int k = 0; k < 128; k += 4) {
      const float4 hv = *(const float4*)&h1s[k];
      acc += hv.x * Wc2t[(k + 0) * 64 + t];
      acc += hv.y * Wc2t[(k + 1) * 64 + t];
      acc += hv.z * Wc2t[(k + 2) * 64 + t];
      acc += hv.w * Wc2t[(k + 3) * 64 + t];
    }
    float v = fmaxf(acc, 0.f) * Wc3[t];
#pragma unroll
    for (int o = 32; o > 0; o >>= 1) v += __shfl_down(v, o);
    if (t == 0) out[b] = v + bc3[0];
  }
}

extern "C" void kernel_launch(void* const* d_in, const int* in_sizes, int n_in,
                              void* d_out, int out_size, void* d_ws, size_t ws_size,
                              hipStream_t stream) {
  const int* indices = (const int*)d_in[0];
  const int* src = (const int*)d_in[1];
  const int* dst = (const int*)d_in[2];
  const float* w = (const float*)d_in[3];
  const float* ndata = (const float*)d_in[4];
  const float* W1 = (const float*)d_in[5];
  const float* b1 = (const float*)d_in[6];
  const float* W2 = (const float*)d_in[7];
  const float* b2 = (const float*)d_in[8];
  const float* eps = (const float*)d_in[9];
  const float* Wc1 = (const float*)d_in[10];
  const float* bc1 = (const float*)d_in[11];
  const float* Wc2 = (const float*)d_in[12];
  const float* bc2 = (const float*)d_in[13];
  const float* Wc3 = (const float*)d_in[14];
  const float* bc3 = (const float*)d_in[15];
  float* out = (float*)d_out;

  const int E = in_sizes[1];
  const int N = in_sizes[4] / 128;
  const int B = in_sizes[0] / 23;

  char* ws = (char*)d_ws;
  size_t off = 0;
  auto alloc = [&](size_t bytes) -> char* {
    char* p = ws + off;
    off = (off + bytes + 255) & ~(size_t)255;
    return p;
  };
  int* cnt = (int*)alloc((size_t)N * 4);
  int* rowptr = (int*)alloc((size_t)(N + 1) * 4);
  int* cursor = (int*)alloc((size_t)N * 4);
  int* bsum = (int*)alloc(256 * 4);
  int2* epack = (int2*)alloc((size_t)E * 8);
  float* x1 = (float*)alloc((size_t)N * 128 * 4);
  float* x2 = (float*)alloc((size_t)N * 128 * 4);
  float* Wt1 = (float*)alloc(16384 * 4);
  float* Wt2 = (float*)alloc(16384 * 4);
  float* Wc1t = (float*)alloc(49152 * 4);
  float* Wc2t = (float*)alloc(8192 * 4);

  hipMemsetAsync(cnt, 0, (size_t)N * 4, stream);
  hipMemsetAsync(cursor, 0, (size_t)N * 4, stream);

  prep_transpose<<<(90112 + 255) / 256, 256, 0, stream>>>(W1, W2, Wc1, Wc2, Wt1, Wt2, Wc1t, Wc2t);
  hist_kernel<<<(E + 255) / 256, 256, 0, stream>>>(dst, cnt, E);
  const int nchunk = (N + 2047) / 2048;
  scan1_kernel<<<nchunk, 256, 0, stream>>>(cnt, rowptr, bsum, N);
  scan2_kernel<<<1, 64, 0, stream>>>(bsum, nchunk);
  scan3_kernel<<<(N + 255) / 256, 256, 0, stream>>>(rowptr, bsum, N, E);
  scatter_kernel<<<(E + 255) / 256, 256, 0, stream>>>(src, dst, w, rowptr, cursor, epack, E);

  const int nconv = (N + CONV_NPB - 1) / CONV_NPB;
  conv_kernel<<<nconv, 256, 0, stream>>>(ndata, x1, rowptr, epack, Wt1, b1, eps, 0, 1, 0, N);
  conv_kernel<<<nconv, 256, 0, stream>>>(x1, x2, rowptr, epack, Wt2, b2, eps, 1, 0, 1, N);

  final_kernel<<<B, 128, 0, stream>>>(x2, indices, Wc1t, bc1, Wc2t, bc2, Wc3, bc3, out);
}

// Round 3
// 641.317 us; speedup vs baseline: 1.4593x; 1.0643x over previous
//
#include <hip/hip_runtime.h>

// GIN_MLP: 2x GIN conv (N=100000, E=1.6M, H=128) + per-batch context MLP (B=4096).
// Device-built dst-CSR -> fused aggregate+GEMM -> per-batch MLP. All f32.
// R3: edge-balanced stage-1 (contiguous CSR edge range split into 8 equal
// laneset chunks, LDS atomic flush at row boundaries), NPB=32, 8 blocks/CU.

#define CONV_NPB 32

__global__ void prep_transpose(const float* __restrict__ W1, const float* __restrict__ W2,
                               const float* __restrict__ Wc1, const float* __restrict__ Wc2,
                               float* __restrict__ Wt1, float* __restrict__ Wt2,
                               float* __restrict__ Wc1t, float* __restrict__ Wc2t) {
  int i = blockIdx.x * blockDim.x + threadIdx.x;
  if (i < 16384) {
    int f = i >> 7, k = i & 127;
    Wt1[k * 128 + f] = W1[i];
  } else if (i < 32768) {
    int j = i - 16384; int f = j >> 7, k = j & 127;
    Wt2[k * 128 + f] = W2[j];
  } else if (i < 81920) {
    int j = i - 32768; int f = j / 384, k = j % 384;
    Wc1t[k * 128 + f] = Wc1[j];
  } else if (i < 90112) {
    int j = i - 81920; int f = j >> 7, k = j & 127;
    Wc2t[k * 64 + f] = Wc2[j];
  }
}

__global__ void hist_kernel(const int* __restrict__ dst, int* __restrict__ cnt, int E) {
  int e = blockIdx.x * blockDim.x + threadIdx.x;
  if (e < E) atomicAdd(&cnt[dst[e]], 1);
}

// per-2048-chunk exclusive scan; bsum[b] = chunk total
__global__ void scan1_kernel(const int* __restrict__ cnt, int* __restrict__ rowptr,
                             int* __restrict__ bsum, int n) {
  __shared__ int smem[256];
  const int t = threadIdx.x;
  const int base = blockIdx.x * 2048 + t * 8;
  int v[8];
  int s = 0;
#pragma unroll
  for (int j = 0; j < 8; ++j) {
    int idx = base + j;
    v[j] = (idx < n) ? cnt[idx] : 0;
    s += v[j];
  }
  smem[t] = s;
  __syncthreads();
  for (int off = 1; off < 256; off <<= 1) {
    int add = (t >= off) ? smem[t - off] : 0;
    __syncthreads();
    smem[t] += add;
    __syncthreads();
  }
  int run = smem[t] - s;
  if (t == 255) bsum[blockIdx.x] = smem[255];
#pragma unroll
  for (int j = 0; j < 8; ++j) {
    int idx = base + j;
    if (idx < n) rowptr[idx] = run;
    run += v[j];
  }
}

// 64-lane shuffle scan (nb <= 64 fast path; serial fallback otherwise)
__global__ void scan2_kernel(int* __restrict__ bsum, int nb) {
  const int t = threadIdx.x;
  if (nb <= 64) {
    const int orig = (t < nb) ? bsum[t] : 0;
    int v = orig;
#pragma unroll
    for (int off = 1; off < 64; off <<= 1) {
      int u = __shfl_up(v, off);
      if (t >= off) v += u;
    }
    if (t < nb) bsum[t] = v - orig;
  } else if (t == 0) {
    int run = 0;
    for (int i = 0; i < nb; ++i) { int v = bsum[i]; bsum[i] = run; run += v; }
  }
}

__global__ void scan3_kernel(int* __restrict__ rowptr, const int* __restrict__ bsum,
                             int n, int E) {
  int i = blockIdx.x * blockDim.x + threadIdx.x;
  if (i < n) rowptr[i] += bsum[i >> 11];
  if (i == 0) rowptr[n] = E;
}

// packs (src, bitcast(w)) so the conv edge stream is one 8B load per edge
__global__ void scatter_kernel(const int* __restrict__ src, const int* __restrict__ dst,
                               const float* __restrict__ w, const int* __restrict__ rowptr,
                               int* __restrict__ cursor, int2* __restrict__ epack, int E) {
  int e = blockIdx.x * blockDim.x + threadIdx.x;
  if (e < E) {
    int d = dst[e];
    int pos = rowptr[d] + atomicAdd(&cursor[d], 1);
    epack[pos] = make_int2(src[e], __float_as_int(w[e]));
  }
}

// Stage 1: the block's 32 rows have a CONTIGUOUS edge range [rp[0], rp[32]).
// Split it into 8 equal chunks, one per 32-lane laneset; each laneset walks
// edges linearly (lane = 4 features), accumulating in registers and flushing
// to LDS xm via atomicAdd only at row boundaries. Perfect edge balance.
// Stage 2: finalize (1+eps)x + agg/deg. Stage 3: 32x128 @ 128x128 GEMM.
__launch_bounds__(256, 8)
__global__ void conv_kernel(const float* __restrict__ xin, float* __restrict__ xout,
                            const int* __restrict__ rowptr, const int2* __restrict__ epack,
                            const float* __restrict__ Wt,
                            const float* __restrict__ bias, const float* __restrict__ eps,
                            int epsidx, int dorelu, int zerorow0, int n) {
  __shared__ float xm[CONV_NPB * 128];
  __shared__ int rp_s[CONV_NPB + 1];
  const int t = threadIdx.x;
  const int nb = blockIdx.x * CONV_NPB;
  const float epsv = 1.0f + eps[epsidx];

  // zero accumulator tile + cache rowptr slice
#pragma unroll
  for (int i = 0; i < 4; ++i)
    *(float4*)&xm[(t + i * 256) * 4] = make_float4(0.f, 0.f, 0.f, 0.f);
  if (t <= CONV_NPB) {
    int node = nb + t;
    rp_s[t] = rowptr[node <= n ? node : n];
  }
  __syncthreads();

  // ---- stage 1: edge-balanced gather ----
  {
    const int L = t >> 5;         // laneset 0..7
    const int lane = t & 31;
    const int f0 = lane * 4;
    const int e0 = rp_s[0], e1 = rp_s[CONV_NPB];
    const int total = e1 - e0;
    const int chunk = (total + 7) >> 3;
    int j = e0 + L * chunk;
    const int j1 = min(j + chunk, e1);
    int r = 0;
    while (j < j1) {
      while (rp_s[r + 1] <= j) ++r;            // advance to j's row
      const int re = min(rp_s[r + 1], j1);
      float ax = 0.f, ay = 0.f, az = 0.f, aw = 0.f;
      int jj = j;
      for (; jj + 4 <= re; jj += 4) {
        const int2 p0 = epack[jj + 0];
        const int2 p1 = epack[jj + 1];
        const int2 p2 = epack[jj + 2];
        const int2 p3 = epack[jj + 3];
        const float4 a0 = *(const float4*)&xin[(size_t)p0.x * 128 + f0];
        const float4 a1 = *(const float4*)&xin[(size_t)p1.x * 128 + f0];
        const float4 a2 = *(const float4*)&xin[(size_t)p2.x * 128 + f0];
        const float4 a3 = *(const float4*)&xin[(size_t)p3.x * 128 + f0];
        const float w0 = __int_as_float(p0.y), w1 = __int_as_float(p1.y);
        const float w2 = __int_as_float(p2.y), w3 = __int_as_float(p3.y);
        ax += w0 * a0.x + w1 * a1.x + w2 * a2.x + w3 * a3.x;
        ay += w0 * a0.y + w1 * a1.y + w2 * a2.y + w3 * a3.y;
        az += w0 * a0.z + w1 * a1.z + w2 * a2.z + w3 * a3.z;
        aw += w0 * a0.w + w1 * a1.w + w2 * a2.w + w3 * a3.w;
      }
      for (; jj < re; ++jj) {
        const int2 p = epack[jj];
        const float4 a = *(const float4*)&xin[(size_t)p.x * 128 + f0];
        const float wv = __int_as_float(p.y);
        ax += wv * a.x; ay += wv * a.y; az += wv * a.z; aw += wv * a.w;
      }
      float* dstp = &xm[r * 128 + f0];
      atomicAdd(dstp + 0, ax);
      atomicAdd(dstp + 1, ay);
      atomicAdd(dstp + 2, az);
      atomicAdd(dstp + 3, aw);
      j = re;
    }
  }
  __syncthreads();

  // ---- stage 2: finalize (1+eps)*x + agg/deg ----
  {
#pragma unroll
    for (int q = 0; q < 4; ++q) {
      const int task = t + q * 256;           // 32 rows x 32 fgroups = 1024
      const int r = task >> 5;
      const int f0 = (task & 31) * 4;
      const int node = nb + r;
      if (node < n) {
        const int d = rp_s[r + 1] - rp_s[r];
        const float rdeg = 1.0f / (float)(d > 1 ? d : 1);
        const float4 xv = *(const float4*)&xin[(size_t)node * 128 + f0];
        float4 m = *(const float4*)&xm[r * 128 + f0];
        m.x = epsv * xv.x + m.x * rdeg;
        m.y = epsv * xv.y + m.y * rdeg;
        m.z = epsv * xv.z + m.z * rdeg;
        m.w = epsv * xv.w + m.w * rdeg;
        *(float4*)&xm[r * 128 + f0] = m;
      }
    }
  }
  __syncthreads();

  // ---- stage 3: GEMM, thread tile = 4 rows x 4 features ----
  {
    const int fg = t & 31;
    const int rg = t >> 5;
    const int f0 = fg * 4;
    const int r0 = rg * 4;
    float4 acc[4];
#pragma unroll
    for (int r = 0; r < 4; ++r) acc[r] = make_float4(0.f, 0.f, 0.f, 0.f);
    for (int k = 0; k < 128; k += 4) {
      const float4 w0 = *(const float4*)&Wt[(k + 0) * 128 + f0];
      const float4 w1 = *(const float4*)&Wt[(k + 1) * 128 + f0];
      const float4 w2 = *(const float4*)&Wt[(k + 2) * 128 + f0];
      const float4 w3 = *(const float4*)&Wt[(k + 3) * 128 + f0];
#pragma unroll
      for (int r = 0; r < 4; ++r) {
        const float4 xv = *(const float4*)&xm[(r0 + r) * 128 + k];
        acc[r].x += xv.x * w0.x + xv.y * w1.x + xv.z * w2.x + xv.w * w3.x;
        acc[r].y += xv.x * w0.y + xv.y * w1.y + xv.z * w2.y + xv.w * w3.y;
        acc[r].z += xv.x * w0.z + xv.y * w1.z + xv.z * w2.z + xv.w * w3.z;
        acc[r].w += xv.x * w0.w + xv.y * w1.w + xv.z * w2.w + xv.w * w3.w;
      }
    }
    const float4 bv = *(const float4*)&bias[f0];
#pragma unroll
    for (int r = 0; r < 4; ++r) {
      const int node = nb + r0 + r;
      if (node < n) {
        float4 v;
        v.x = acc[r].x + bv.x;
        v.y = acc[r].y + bv.y;
        v.z = acc[r].z + bv.z;
        v.w = acc[r].w + bv.w;
        if (dorelu) {
          v.x = fmaxf(v.x, 0.f); v.y = fmaxf(v.y, 0.f);
          v.z = fmaxf(v.z, 0.f); v.w = fmaxf(v.w, 0.f);
        }
        if (zerorow0 && node == 0) { v.x = 0.f; v.y = 0.f; v.z = 0.f; v.w = 0.f; }
        *(float4*)&xout[(size_t)node * 128 + f0] = v;
      }
    }
  }
}

// One block (128 thr) per batch element: gather ing1/ing2/ctx into LDS, MLP 384->128->64->1.
__launch_bounds__(128, 4)
__global__ void final_kernel(const float* __restrict__ x2, const int* __restrict__ indices,
                             const float* __restrict__ Wc1t, const float* __restrict__ bc1,
                             const float* __restrict__ Wc2t, const float* __restrict__ bc2,
                             const float* __restrict__ Wc3, const float* __restrict__ bc3,
                             float* __restrict__ out) {
  __shared__ float ysm[384];
  __shared__ float h1s[128];
  const int b = blockIdx.x;
  const int t = threadIdx.x;
  const int* ind = indices + (size_t)b * 23;

  {
    const int i0 = ind[0];
    const int i1 = ind[1];
    ysm[t] = x2[(size_t)i0 * 128 + t];
    ysm[128 + t] = x2[(size_t)i1 * 128 + t];
    float cs = 0.f;
    int cc = 0;
#pragma unroll
    for (int j = 0; j < 20; ++j) {
      const int cj = ind[3 + j];
      cc += (cj > 0) ? 1 : 0;
      cs += x2[(size_t)cj * 128 + t];
    }
    ysm[256 + t] = cs / (float)(cc > 0 ? cc : 1);
  }
  __syncthreads();

  {
    float acc = bc1[t];
    for (int k = 0; k < 384; k += 4) {
      const float4 yv = *(const float4*)&ysm[k];
      acc += yv.x * Wc1t[(k + 0) * 128 + t];
      acc += yv.y * Wc1t[(k + 1) * 128 + t];
      acc += yv.z * Wc1t[(k + 2) * 128 + t];
      acc += yv.w * Wc1t[(k + 3) * 128 + t];
    }
    h1s[t] = fmaxf(acc, 0.f);
  }
  __syncthreads();

  if (t < 64) {
    float acc = bc2[t];
    for (int k = 0; k < 128; k += 4) {
      const float4 hv = *(const float4*)&h1s[k];
      acc += hv.x * Wc2t[(k + 0) * 64 + t];
      acc += hv.y * Wc2t[(k + 1) * 64 + t];
      acc += hv.z * Wc2t[(k + 2) * 64 + t];
      acc += hv.w * Wc2t[(k + 3) * 64 + t];
    }
    float v = fmaxf(acc, 0.f) * Wc3[t];
#pragma unroll
    for (int o = 32; o > 0; o >>= 1) v += __shfl_down(v, o);
    if (t == 0) out[b] = v + bc3[0];
  }
}

extern "C" void kernel_launch(void* const* d_in, const int* in_sizes, int n_in,
                              void* d_out, int out_size, void* d_ws, size_t ws_size,
                              hipStream_t stream) {
  const int* indices = (const int*)d_in[0];
  const int* src = (const int*)d_in[1];
  const int* dst = (const int*)d_in[2];
  const float* w = (const float*)d_in[3];
  const float* ndata = (const float*)d_in[4];
  const float* W1 = (const float*)d_in[5];
  const float* b1 = (const float*)d_in[6];
  const float* W2 = (const float*)d_in[7];
  const float* b2 = (const float*)d_in[8];
  const float* eps = (const float*)d_in[9];
  const float* Wc1 = (const float*)d_in[10];
  const float* bc1 = (const float*)d_in[11];
  const float* Wc2 = (const float*)d_in[12];
  const float* bc2 = (const float*)d_in[13];
  const float* Wc3 = (const float*)d_in[14];
  const float* bc3 = (const float*)d_in[15];
  float* out = (float*)d_out;

  const int E = in_sizes[1];
  const int N = in_sizes[4] / 128;
  const int B = in_sizes[0] / 23;

  char* ws = (char*)d_ws;
  size_t off = 0;
  auto alloc = [&](size_t bytes) -> char* {
    char* p = ws + off;
    off = (off + bytes + 255) & ~(size_t)255;
    return p;
  };
  int* cnt = (int*)alloc((size_t)N * 4);
  int* rowptr = (int*)alloc((size_t)(N + 1) * 4);
  int* cursor = (int*)alloc((size_t)N * 4);
  int* bsum = (int*)alloc(256 * 4);
  int2* epack = (int2*)alloc((size_t)E * 8);
  float* x1 = (float*)alloc((size_t)N * 128 * 4);
  float* x2 = (float*)alloc((size_t)N * 128 * 4);
  float* Wt1 = (float*)alloc(16384 * 4);
  float* Wt2 = (float*)alloc(16384 * 4);
  float* Wc1t = (float*)alloc(49152 * 4);
  float* Wc2t = (float*)alloc(8192 * 4);

  hipMemsetAsync(cnt, 0, (size_t)N * 4, stream);
  hipMemsetAsync(cursor, 0, (size_t)N * 4, stream);

  prep_transpose<<<(90112 + 255) / 256, 256, 0, stream>>>(W1, W2, Wc1, Wc2, Wt1, Wt2, Wc1t, Wc2t);
  hist_kernel<<<(E + 255) / 256, 256, 0, stream>>>(dst, cnt, E);
  const int nchunk = (N + 2047) / 2048;
  scan1_kernel<<<nchunk, 256, 0, stream>>>(cnt, rowptr, bsum, N);
  scan2_kernel<<<1, 64, 0, stream>>>(bsum, nchunk);
  scan3_kernel<<<(N + 255) / 256, 256, 0, stream>>>(rowptr, bsum, N, E);
  scatter_kernel<<<(E + 255) / 256, 256, 0, stream>>>(src, dst, w, rowptr, cursor, epack, E);

  const int nconv = (N + CONV_NPB - 1) / CONV_NPB;
  conv_kernel<<<nconv, 256, 0, stream>>>(ndata, x1, rowptr, epack, Wt1, b1, eps, 0, 1, 0, N);
  conv_kernel<<<nconv, 256, 0, stream>>>(x1, x2, rowptr, epack, Wt2, b2, eps, 1, 0, 1, N);

  final_kernel<<<B, 128, 0, stream>>>(x2, indices, Wc1t, bc1, Wc2t, bc2, Wc3, bc3, out);
}